// Round 1
// baseline (1086.260 us; speedup 1.0000x reference)
//
#include <hip/hip_runtime.h>
#include <hip/hip_bf16.h>
#include <math.h>

#define NB   16
#define C1   256
#define C2   256
#define NK   5
#define NEXP (C2 * NK)   // 1280
#define HH   64
#define WW   64
#define HW   4096

// ---------------------------------------------------------------------------
// Kernel 0: fold the 3 paths: weff[k][c][t] = sum_p w_path[p][k][c][0][t]
// w_path flat layout: ((p*NK + k)*C2 + c)*9 + t
// weff  flat layout:  ((k*C2 + c)*9 + t)
// ---------------------------------------------------------------------------
__global__ void weff_kernel(const float* __restrict__ w_path, float* __restrict__ weff) {
    int idx = blockIdx.x * 256 + threadIdx.x;
    if (idx >= NK * C2 * 9) return;
    float s = 0.f;
    #pragma unroll
    for (int p = 0; p < 3; ++p)
        s += w_path[(long)p * NK * C2 * 9 + idx];
    weff[idx] = s;
}

// ---------------------------------------------------------------------------
// Tiled fp32 SGEMM:  C[m][n] = sum_k A[m][k] * B[k][n]   (per batch z)
// Tile 64x64, K-step 16, 256 threads, 4x4 microtile.
// OUT_BF16: store bf16 (expand stage).  else: BN + SiLU epilogue, fp32 out.
// B batch index = bOffB + z;  C batch index = bOffC + z.
// ---------------------------------------------------------------------------
template <bool OUT_BF16>
__global__ __launch_bounds__(256)
void gemm_tile_kernel(const float* __restrict__ A, const float* __restrict__ B_all,
                      void* __restrict__ C_all, int M, int K, int N,
                      long bStrideB, long bStrideC, int bOffB, int bOffC,
                      const float* __restrict__ bn_gamma, const float* __restrict__ bn_beta,
                      const float* __restrict__ bn_mean, const float* __restrict__ bn_var) {
    __shared__ float As[16][64];   // [k][m]
    __shared__ float Bs[16][64];   // [k][n]
    const int z  = blockIdx.z;
    const float* B = B_all + (long)(bOffB + z) * bStrideB;
    const int n0 = blockIdx.x * 64;
    const int m0 = blockIdx.y * 64;
    const int t  = threadIdx.x;
    const int tm = t / 16, tn = t % 16;
    const int alm = t >> 2;            // 0..63  (m within tile)
    const int alk = (t & 3) * 4;       // 0..12  (k within tile)
    const int blk = t >> 4;            // 0..15  (k)
    const int bln = (t & 15) * 4;      // 0..60  (n)

    float acc[4][4] = {};

    for (int k0 = 0; k0 < K; k0 += 16) {
        float4 av = *reinterpret_cast<const float4*>(&A[(long)(m0 + alm) * K + k0 + alk]);
        As[alk + 0][alm] = av.x;
        As[alk + 1][alm] = av.y;
        As[alk + 2][alm] = av.z;
        As[alk + 3][alm] = av.w;
        float4 bv = *reinterpret_cast<const float4*>(&B[(long)(k0 + blk) * N + n0 + bln]);
        *reinterpret_cast<float4*>(&Bs[blk][bln]) = bv;
        __syncthreads();
        #pragma unroll
        for (int k = 0; k < 16; ++k) {
            float4 a  = *reinterpret_cast<const float4*>(&As[k][tm * 4]);
            float4 bb = *reinterpret_cast<const float4*>(&Bs[k][tn * 4]);
            float ar[4] = {a.x, a.y, a.z, a.w};
            float br[4] = {bb.x, bb.y, bb.z, bb.w};
            #pragma unroll
            for (int i = 0; i < 4; ++i)
                #pragma unroll
                for (int j = 0; j < 4; ++j)
                    acc[i][j] += ar[i] * br[j];
        }
        __syncthreads();
    }

    if constexpr (OUT_BF16) {
        __hip_bfloat16* C = (__hip_bfloat16*)C_all + (long)(bOffC + z) * bStrideC;
        #pragma unroll
        for (int i = 0; i < 4; ++i) {
            long m = m0 + tm * 4 + i;
            #pragma unroll
            for (int j = 0; j < 4; ++j)
                C[m * N + n0 + tn * 4 + j] = __float2bfloat16(acc[i][j]);
        }
    } else {
        float* C = (float*)C_all + (long)(bOffC + z) * bStrideC;
        #pragma unroll
        for (int i = 0; i < 4; ++i) {
            int m = m0 + tm * 4 + i;
            float scale = bn_gamma[m] * rsqrtf(bn_var[m] + 1e-5f);
            float mn = bn_mean[m], bt = bn_beta[m];
            #pragma unroll
            for (int j = 0; j < 4; ++j) {
                float v = (acc[i][j] - mn) * scale + bt;
                float o = v / (1.0f + __expf(-v));     // SiLU
                C[(long)m * N + n0 + tn * 4 + j] = o;
            }
        }
    }
}

// ---------------------------------------------------------------------------
// Kernel 2: circular roll (per shift group) + zero-padded depthwise 3x3 + sum
// over the 5 shift groups.
// merged[z][c][i][j] = sum_k sum_{u,v} weff[k][c][u*3+v] *
//     ((i+u-1) in [0,64) && (j+v-1) in [0,64)
//        ? xexp[z][c*5+k][(i+u-1-s_k)&63][(j+v-1-s_k)&63] : 0)
// ---------------------------------------------------------------------------
__global__ __launch_bounds__(256)
void shift_dw_merge_kernel(const __hip_bfloat16* __restrict__ xexp,
                           const float* __restrict__ weff,
                           float* __restrict__ merged) {
    const int j = threadIdx.x;                       // 0..63
    const int i = blockIdx.x * 4 + threadIdx.y;      // 0..63
    const int c = blockIdx.y;
    const int z = blockIdx.z;
    const int shifts[NK] = {-4, -1, 2, 5, 8};

    const __hip_bfloat16* base = xexp + ((long)z * NEXP + (long)c * NK) * HW;
    float acc = 0.f;
    #pragma unroll
    for (int k = 0; k < NK; ++k) {
        const int s = shifts[k];
        const __hip_bfloat16* xk = base + (long)k * HW;
        const float* wk = weff + ((long)k * C2 + c) * 9;
        #pragma unroll
        for (int u = 0; u < 3; ++u) {
            int p = i + u - 1;
            if (p < 0 || p >= HH) continue;
            int pr = (p - s) & 63;
            #pragma unroll
            for (int v = 0; v < 3; ++v) {
                int q = j + v - 1;
                if (q < 0 || q >= WW) continue;
                int qr = (q - s) & 63;
                acc += wk[u * 3 + v] * __bfloat162float(xk[pr * WW + qr]);
            }
        }
    }
    merged[((long)z * C2 + c) * HW + i * WW + j] = acc;
}

// ---------------------------------------------------------------------------
extern "C" void kernel_launch(void* const* d_in, const int* in_sizes, int n_in,
                              void* d_out, int out_size, void* d_ws, size_t ws_size,
                              hipStream_t stream) {
    const float* x        = (const float*)d_in[0];
    const float* w_expand = (const float*)d_in[1];
    const float* w_path   = (const float*)d_in[2];
    const float* w_mix    = (const float*)d_in[3];
    const float* bn_gamma = (const float*)d_in[4];
    const float* bn_beta  = (const float*)d_in[5];
    const float* bn_mean  = (const float*)d_in[6];
    const float* bn_var   = (const float*)d_in[7];

    char* ws = (char*)d_ws;
    // weff lives at ws[0 .. 46080)
    float* weff = (float*)ws;
    const size_t weff_reserve = 65536;
    const size_t xexp_per_b   = (size_t)NEXP * HW * sizeof(__hip_bfloat16); // 10.0 MB
    const size_t merged_per_b = (size_t)C2 * HW * sizeof(float);            // 4.0 MB
    const size_t per_b = xexp_per_b + merged_per_b;                         // 14.0 MB

    // batch group size that fits the workspace (16 needs ~225 MB)
    int g = 1;
    if (ws_size > weff_reserve + per_b) {
        size_t fit = (ws_size - weff_reserve) / per_b;
        g = (int)(fit < 16 ? fit : 16);
        if (g < 1) g = 1;
    }

    __hip_bfloat16* xexp = (__hip_bfloat16*)(ws + weff_reserve);
    float* merged = (float*)(ws + weff_reserve + (size_t)g * xexp_per_b);

    weff_kernel<<<(NK * C2 * 9 + 255) / 256, 256, 0, stream>>>(w_path, weff);

    for (int b0 = 0; b0 < NB; b0 += g) {
        int gb = (NB - b0) < g ? (NB - b0) : g;
        // 1) expand: A = w_expand [1280x256], B = x[b] [256x4096] -> xexp bf16
        gemm_tile_kernel<true><<<dim3(HW / 64, NEXP / 64, gb), 256, 0, stream>>>(
            w_expand, x, xexp, NEXP, C1, HW,
            (long)C1 * HW, (long)NEXP * HW, b0, 0,
            nullptr, nullptr, nullptr, nullptr);
        // 2) roll + depthwise 3x3 + merge over k
        shift_dw_merge_kernel<<<dim3(HH / 4, C2, gb), dim3(64, 4), 0, stream>>>(
            xexp, weff, merged);
        // 3) mix GEMM + BN + SiLU -> d_out fp32
        gemm_tile_kernel<false><<<dim3(HW / 64, C2 / 64, gb), 256, 0, stream>>>(
            w_mix, merged, d_out, C2, C2, HW,
            (long)C2 * HW, (long)C2 * HW, 0, b0,
            bn_gamma, bn_beta, bn_mean, bn_var);
    }
}

// Round 2
// 412.945 us; speedup vs baseline: 2.6305x; 2.6305x over previous
//
#include <hip/hip_runtime.h>
#include <hip/hip_bf16.h>
#include <math.h>

#define NB   16
#define C1   256
#define C2   256
#define NK   5
#define NEXP (C2 * NK)   // 1280
#define HW   4096

typedef __attribute__((ext_vector_type(8))) short bf16x8;
typedef __attribute__((ext_vector_type(4))) float f32x4;

// ---------------------------------------------------------------------------
// weff[k][c][t] = sum_p w_path[p][k][c][0][t]
// ---------------------------------------------------------------------------
__global__ void weff_kernel(const float* __restrict__ w_path, float* __restrict__ weff) {
    int idx = blockIdx.x * 256 + threadIdx.x;
    if (idx >= NK * C2 * 9) return;
    float s = 0.f;
    #pragma unroll
    for (int p = 0; p < 3; ++p)
        s += w_path[(long)p * NK * C2 * 9 + idx];
    weff[idx] = s;
}

// fp32 -> bf16 plain convert (weights)
__global__ void cvt_bf16_kernel(const float* __restrict__ in, __hip_bfloat16* __restrict__ out, int n) {
    int i = blockIdx.x * 256 + threadIdx.x;
    if (i < n) out[i] = __float2bfloat16(in[i]);
}

// ---------------------------------------------------------------------------
// Transpose [z][R][C] -> [z][C][R], output bf16.  Block 256 thr, 32x32 tile.
// ---------------------------------------------------------------------------
__device__ inline float ldf(const float v) { return v; }
__device__ inline float ldf(const __hip_bfloat16 v) { return __bfloat162float(v); }

template <typename TIN>
__global__ __launch_bounds__(256)
void transpose_bf16_kernel(const TIN* __restrict__ in, __hip_bfloat16* __restrict__ out,
                           int R, int C, long inStride, long outStride) {
    __shared__ float tile[32][33];
    const int z = blockIdx.z;
    const TIN* src = in + (long)z * inStride;
    __hip_bfloat16* dst = out + (long)z * outStride;
    const int c0 = blockIdx.x * 32;
    const int r0 = blockIdx.y * 32;
    const int tx = threadIdx.x & 31;
    const int ty = threadIdx.x >> 5;   // 0..7
    #pragma unroll
    for (int i = 0; i < 4; ++i)
        tile[ty + i * 8][tx] = ldf(src[(long)(r0 + ty + i * 8) * C + c0 + tx]);
    __syncthreads();
    #pragma unroll
    for (int i = 0; i < 4; ++i)
        dst[(long)(c0 + ty + i * 8) * R + r0 + tx] = __float2bfloat16(tile[tx][ty + i * 8]);
}

// ---------------------------------------------------------------------------
// MFMA bf16 GEMM: C[m][n] = sum_k A[m][k]*B[k][n], B given transposed BT[n][k].
// 128x128 tile, BK=32, 256 threads = 4 waves, each wave 64x64 (4x4 frags).
// ---------------------------------------------------------------------------
template <bool OUT_BF16>
__global__ __launch_bounds__(256)
void gemm_mfma_kernel(const __hip_bfloat16* __restrict__ A,      // [M][K]
                      const __hip_bfloat16* __restrict__ BT_all, // [z][N][K]
                      void* __restrict__ C_all, int M, int N, int K,
                      long bStrideB, long bStrideC, int bOffB, int bOffC,
                      const float* __restrict__ bn_gamma, const float* __restrict__ bn_beta,
                      const float* __restrict__ bn_mean, const float* __restrict__ bn_var) {
    __shared__ __align__(16) short As[128 * 32];
    __shared__ __align__(16) short Bs[128 * 32];
    const int z = blockIdx.z;
    const __hip_bfloat16* BT = BT_all + (long)(bOffB + z) * bStrideB;
    const int n0 = blockIdx.x * 128;
    const int m0 = blockIdx.y * 128;
    const int t = threadIdx.x;
    const int lane = t & 63;
    const int wid = t >> 6;
    const int wr = wid >> 1, wc = wid & 1;
    const int lr = lane & 15, lg = lane >> 4;
    const int sr = t >> 2;        // staging row 0..63
    const int sc = (t & 3) * 8;   // staging k-offset

    f32x4 acc[4][4];
    #pragma unroll
    for (int i = 0; i < 4; ++i)
        #pragma unroll
        for (int j = 0; j < 4; ++j)
            acc[i][j] = (f32x4){0.f, 0.f, 0.f, 0.f};

    for (int k0 = 0; k0 < K; k0 += 32) {
        bf16x8 a0 = *(const bf16x8*)&A[(long)(m0 + sr) * K + k0 + sc];
        bf16x8 a1 = *(const bf16x8*)&A[(long)(m0 + 64 + sr) * K + k0 + sc];
        bf16x8 b0 = *(const bf16x8*)&BT[(long)(n0 + sr) * K + k0 + sc];
        bf16x8 b1 = *(const bf16x8*)&BT[(long)(n0 + 64 + sr) * K + k0 + sc];
        __syncthreads();           // prev iter's LDS reads done before overwrite
        *(bf16x8*)&As[sr * 32 + sc] = a0;
        *(bf16x8*)&As[(64 + sr) * 32 + sc] = a1;
        *(bf16x8*)&Bs[sr * 32 + sc] = b0;
        *(bf16x8*)&Bs[(64 + sr) * 32 + sc] = b1;
        __syncthreads();
        bf16x8 af[4], bfr[4];
        #pragma unroll
        for (int i = 0; i < 4; ++i) {
            af[i]  = *(const bf16x8*)&As[(wr * 64 + i * 16 + lr) * 32 + lg * 8];
            bfr[i] = *(const bf16x8*)&Bs[(wc * 64 + i * 16 + lr) * 32 + lg * 8];
        }
        #pragma unroll
        for (int i = 0; i < 4; ++i)
            #pragma unroll
            for (int j = 0; j < 4; ++j)
                acc[i][j] = __builtin_amdgcn_mfma_f32_16x16x32_bf16(af[i], bfr[j], acc[i][j], 0, 0, 0);
    }

    // C/D layout: col = lane&15, row = (lane>>4)*4 + reg   [m89-verified]
    if constexpr (OUT_BF16) {
        __hip_bfloat16* C = (__hip_bfloat16*)C_all + (long)(bOffC + z) * bStrideC;
        #pragma unroll
        for (int i = 0; i < 4; ++i) {
            #pragma unroll
            for (int r = 0; r < 4; ++r) {
                long row = m0 + wr * 64 + i * 16 + lg * 4 + r;
                #pragma unroll
                for (int j = 0; j < 4; ++j)
                    C[row * N + n0 + wc * 64 + j * 16 + lr] = __float2bfloat16(acc[i][j][r]);
            }
        }
    } else {
        float* C = (float*)C_all + (long)(bOffC + z) * bStrideC;
        #pragma unroll
        for (int i = 0; i < 4; ++i) {
            #pragma unroll
            for (int r = 0; r < 4; ++r) {
                int row = m0 + wr * 64 + i * 16 + lg * 4 + r;
                float scale = bn_gamma[row] * rsqrtf(bn_var[row] + 1e-5f);
                float mn = bn_mean[row], bt = bn_beta[row];
                #pragma unroll
                for (int j = 0; j < 4; ++j) {
                    float v = (acc[i][j][r] - mn) * scale + bt;
                    C[(long)row * N + n0 + wc * 64 + j * 16 + lr] = v / (1.0f + __expf(-v));
                }
            }
        }
    }
}

// ---------------------------------------------------------------------------
// Stage 2: roll + zero-padded depthwise 3x3 + sum over 5 shift groups.
// Block (64,4) covers 4 rows x 64 cols for one (c, z). LDS-stage 6 rolled rows
// per shift group; roll rows at load, roll columns at consume.
// ---------------------------------------------------------------------------
__global__ __launch_bounds__(256)
void shift_dw_kernel(const __hip_bfloat16* __restrict__ xexp,  // [z][1280][4096]
                     const float* __restrict__ weff,           // [5][256][9]
                     __hip_bfloat16* __restrict__ merged) {    // [z][256][4096]
    __shared__ __align__(16) __hip_bfloat16 sd[5 * 6 * 64];
    const int j = threadIdx.x;                  // 0..63
    const int ty = threadIdx.y;                 // 0..3
    const int t = ty * 64 + j;
    const int i0 = blockIdx.x * 4;
    const int c = blockIdx.y;
    const int z = blockIdx.z;
    const int shifts[NK] = {-4, -1, 2, 5, 8};

    if (t < 240) {                              // 30 rows x 8 chunks of 8 bf16
        int r = t >> 3, ch = (t & 7) * 8;
        int k = r / 6, rr = r % 6;
        int grow = (i0 - 1 + rr - shifts[k]) & 63;
        const __hip_bfloat16* src = xexp + ((long)z * NEXP + (long)c * NK + k) * HW + grow * 64 + ch;
        *(bf16x8*)&sd[(k * 6 + rr) * 64 + ch] = *(const bf16x8*)src;
    }
    __syncthreads();

    const int i = i0 + ty;
    float acc = 0.f;
    #pragma unroll
    for (int k = 0; k < NK; ++k) {
        const float* wk = &weff[((long)k * C2 + c) * 9];
        const int s = shifts[k];
        #pragma unroll
        for (int u = 0; u < 3; ++u) {
            int p = i + u - 1;
            if (p < 0 || p >= 64) continue;
            int rr = ty + u;
            #pragma unroll
            for (int v = 0; v < 3; ++v) {
                int q = j + v - 1;
                if (q < 0 || q >= 64) continue;
                int qr = (q - s) & 63;
                acc += wk[u * 3 + v] * __bfloat162float(sd[(k * 6 + rr) * 64 + qr]);
            }
        }
    }
    merged[((long)z * C2 + c) * HW + i * 64 + j] = __float2bfloat16(acc);
}

// ---------------------------------------------------------------------------
extern "C" void kernel_launch(void* const* d_in, const int* in_sizes, int n_in,
                              void* d_out, int out_size, void* d_ws, size_t ws_size,
                              hipStream_t stream) {
    const float* x        = (const float*)d_in[0];
    const float* w_expand = (const float*)d_in[1];
    const float* w_path   = (const float*)d_in[2];
    const float* w_mix    = (const float*)d_in[3];
    const float* bn_gamma = (const float*)d_in[4];
    const float* bn_beta  = (const float*)d_in[5];
    const float* bn_mean  = (const float*)d_in[6];
    const float* bn_var   = (const float*)d_in[7];

    char* ws = (char*)d_ws;
    float* weff             = (float*)ws;                        // 46080 B
    __hip_bfloat16* wexp_bf = (__hip_bfloat16*)(ws + 65536);     // 655360 B
    __hip_bfloat16* wmix_bf = (__hip_bfloat16*)(ws + 65536 + 655360); // 131072 B
    const size_t head = 1 << 20;

    const size_t xT_per  = (size_t)HW * C1 * 2;        // 2 MB
    const size_t xe_per  = (size_t)NEXP * HW * 2;      // 10 MB
    const size_t mg_per  = (size_t)C2 * HW * 2;        // 2 MB
    const size_t mgT_per = (size_t)HW * C2 * 2;        // 2 MB
    const size_t per_b = xT_per + xe_per + mg_per + mgT_per;   // 16 MB

    int g = 1;
    if (ws_size > head + per_b) {
        size_t fit = (ws_size - head) / per_b;
        g = (int)(fit < NB ? fit : NB);
        if (g < 1) g = 1;
    }

    char* p = ws + head;
    __hip_bfloat16* xTb     = (__hip_bfloat16*)p; p += (size_t)g * xT_per;
    __hip_bfloat16* xexp    = (__hip_bfloat16*)p; p += (size_t)g * xe_per;
    __hip_bfloat16* merged  = (__hip_bfloat16*)p; p += (size_t)g * mg_per;
    __hip_bfloat16* mergedT = (__hip_bfloat16*)p;

    weff_kernel<<<(NK * C2 * 9 + 255) / 256, 256, 0, stream>>>(w_path, weff);
    cvt_bf16_kernel<<<(NEXP * C1 + 255) / 256, 256, 0, stream>>>(w_expand, wexp_bf, NEXP * C1);
    cvt_bf16_kernel<<<(C2 * C2 + 255) / 256, 256, 0, stream>>>(w_mix, wmix_bf, C2 * C2);

    for (int b0 = 0; b0 < NB; b0 += g) {
        int gb = (NB - b0) < g ? (NB - b0) : g;
        // x [z][256][4096] fp32 -> xTb [z][4096][256] bf16
        transpose_bf16_kernel<float><<<dim3(HW / 32, C1 / 32, gb), 256, 0, stream>>>(
            x + (size_t)b0 * C1 * HW, xTb, C1, HW, (long)C1 * HW, (long)HW * C1);
        // expand: [1280x256] x [256x4096] -> xexp bf16 [z][1280][4096]
        gemm_mfma_kernel<true><<<dim3(HW / 128, NEXP / 128, gb), 256, 0, stream>>>(
            wexp_bf, xTb, xexp, NEXP, HW, C1,
            (long)HW * C1, (long)NEXP * HW, 0, 0,
            nullptr, nullptr, nullptr, nullptr);
        // roll + dw3x3 + merge
        shift_dw_kernel<<<dim3(16, C2, gb), dim3(64, 4), 0, stream>>>(xexp, weff, merged);
        // merged [z][256][4096] -> mergedT [z][4096][256]
        transpose_bf16_kernel<__hip_bfloat16><<<dim3(HW / 32, C2 / 32, gb), 256, 0, stream>>>(
            merged, mergedT, C2, HW, (long)C2 * HW, (long)HW * C2);
        // mix + BN + SiLU -> d_out fp32 [z][256][4096]
        gemm_mfma_kernel<false><<<dim3(HW / 128, C2 / 128, gb), 256, 0, stream>>>(
            wmix_bf, mergedT, d_out, C2, HW, C2,
            (long)HW * C2, (long)C2 * HW, 0, b0,
            bn_gamma, bn_beta, bn_mean, bn_var);
    }
}

// Round 3
// 276.178 us; speedup vs baseline: 3.9332x; 1.4952x over previous
//
#include <hip/hip_runtime.h>
#include <hip/hip_bf16.h>
#include <math.h>

#define NB   16
#define C1   256
#define C2   256
#define NK   5
#define NEXP (C2 * NK)   // 1280
#define HW   4096

typedef __attribute__((ext_vector_type(8))) short bf16x8;
typedef __attribute__((ext_vector_type(4))) float f32x4;

#define GLOAD_LDS16(g, l) __builtin_amdgcn_global_load_lds( \
    (const __attribute__((address_space(1))) void*)(g), \
    (__attribute__((address_space(3))) void*)(l), 16, 0, 0)

// ---------------------------------------------------------------------------
// weff[k][c][t] = sum_p w_path[p][k][c][0][t]
// ---------------------------------------------------------------------------
__global__ void weff_kernel(const float* __restrict__ w_path, float* __restrict__ weff) {
    int idx = blockIdx.x * 256 + threadIdx.x;
    if (idx >= NK * C2 * 9) return;
    float s = 0.f;
    #pragma unroll
    for (int p = 0; p < 3; ++p)
        s += w_path[(long)p * NK * C2 * 9 + idx];
    weff[idx] = s;
}

__global__ void cvt_bf16_kernel(const float* __restrict__ in, __hip_bfloat16* __restrict__ out, int n) {
    int i = blockIdx.x * 256 + threadIdx.x;
    if (i < n) out[i] = __float2bfloat16(in[i]);
}

// ---------------------------------------------------------------------------
// Transpose [z][R][C] -> [z][C][R], output bf16.
// ---------------------------------------------------------------------------
__device__ inline float ldf(const float v) { return v; }
__device__ inline float ldf(const __hip_bfloat16 v) { return __bfloat162float(v); }

template <typename TIN>
__global__ __launch_bounds__(256)
void transpose_bf16_kernel(const TIN* __restrict__ in, __hip_bfloat16* __restrict__ out,
                           int R, int C, long inStride, long outStride) {
    __shared__ float tile[32][33];
    const int z = blockIdx.z;
    const TIN* src = in + (long)z * inStride;
    __hip_bfloat16* dst = out + (long)z * outStride;
    const int c0 = blockIdx.x * 32;
    const int r0 = blockIdx.y * 32;
    const int tx = threadIdx.x & 31;
    const int ty = threadIdx.x >> 5;
    #pragma unroll
    for (int i = 0; i < 4; ++i)
        tile[ty + i * 8][tx] = ldf(src[(long)(r0 + ty + i * 8) * C + c0 + tx]);
    __syncthreads();
    #pragma unroll
    for (int i = 0; i < 4; ++i)
        dst[(long)(c0 + ty + i * 8) * R + r0 + tx] = __float2bfloat16(tile[tx][ty + i * 8]);
}

// ---------------------------------------------------------------------------
// MFMA bf16 GEMM, 128x128 tile, BK=32, 4 waves, global_load_lds staging.
// ---------------------------------------------------------------------------
template <bool OUT_BF16>
__global__ __launch_bounds__(256)
void gemm_mfma_kernel(const __hip_bfloat16* __restrict__ A,      // [M][K]
                      const __hip_bfloat16* __restrict__ BT_all, // [z][N][K]
                      void* __restrict__ C_all, int M, int N, int K,
                      long bStrideB, long bStrideC, int bOffB, int bOffC,
                      const float* __restrict__ bn_gamma, const float* __restrict__ bn_beta,
                      const float* __restrict__ bn_mean, const float* __restrict__ bn_var) {
    __shared__ __align__(16) short As[128 * 32];
    __shared__ __align__(16) short Bs[128 * 32];
    const int z = blockIdx.z;
    const __hip_bfloat16* BT = BT_all + (long)(bOffB + z) * bStrideB;
    const int n0 = blockIdx.x * 128;
    const int m0 = blockIdx.y * 128;
    const int t = threadIdx.x;
    const int lane = t & 63;
    const int wid = t >> 6;
    const int wr = wid >> 1, wc = wid & 1;
    const int lr = lane & 15, lg = lane >> 4;
    const int sr = t >> 2;        // staging row 0..63
    const int sc = (t & 3) * 8;   // staging k-offset

    // LDS byte offset for (sr,sc) = (sr*32+sc)*2 = t*16 : lane-linear -> OK
    const __hip_bfloat16* aP0 = &A[(long)(m0 + sr) * K + sc];
    const __hip_bfloat16* aP1 = &A[(long)(m0 + 64 + sr) * K + sc];
    const __hip_bfloat16* bP0 = &BT[(long)(n0 + sr) * K + sc];
    const __hip_bfloat16* bP1 = &BT[(long)(n0 + 64 + sr) * K + sc];
    short* aD0 = &As[sr * 32 + sc];
    short* aD1 = &As[(64 + sr) * 32 + sc];
    short* bD0 = &Bs[sr * 32 + sc];
    short* bD1 = &Bs[(64 + sr) * 32 + sc];

    f32x4 acc[4][4];
    #pragma unroll
    for (int i = 0; i < 4; ++i)
        #pragma unroll
        for (int j = 0; j < 4; ++j)
            acc[i][j] = (f32x4){0.f, 0.f, 0.f, 0.f};

    for (int k0 = 0; k0 < K; k0 += 32) {
        __syncthreads();                 // prior iter's ds_reads complete
        GLOAD_LDS16(aP0 + k0, aD0);
        GLOAD_LDS16(aP1 + k0, aD1);
        GLOAD_LDS16(bP0 + k0, bD0);
        GLOAD_LDS16(bP1 + k0, bD1);
        __syncthreads();                 // drains vmcnt(0) before barrier
        bf16x8 af[4], bfr[4];
        #pragma unroll
        for (int i = 0; i < 4; ++i) {
            af[i]  = *(const bf16x8*)&As[(wr * 64 + i * 16 + lr) * 32 + lg * 8];
            bfr[i] = *(const bf16x8*)&Bs[(wc * 64 + i * 16 + lr) * 32 + lg * 8];
        }
        #pragma unroll
        for (int i = 0; i < 4; ++i)
            #pragma unroll
            for (int j = 0; j < 4; ++j)
                acc[i][j] = __builtin_amdgcn_mfma_f32_16x16x32_bf16(af[i], bfr[j], acc[i][j], 0, 0, 0);
    }

    if constexpr (OUT_BF16) {
        __hip_bfloat16* C = (__hip_bfloat16*)C_all + (long)(bOffC + z) * bStrideC;
        #pragma unroll
        for (int i = 0; i < 4; ++i) {
            #pragma unroll
            for (int r = 0; r < 4; ++r) {
                long row = m0 + wr * 64 + i * 16 + lg * 4 + r;
                #pragma unroll
                for (int j = 0; j < 4; ++j)
                    C[row * N + n0 + wc * 64 + j * 16 + lr] = __float2bfloat16(acc[i][j][r]);
            }
        }
    } else {
        float* C = (float*)C_all + (long)(bOffC + z) * bStrideC;
        #pragma unroll
        for (int i = 0; i < 4; ++i) {
            #pragma unroll
            for (int r = 0; r < 4; ++r) {
                int row = m0 + wr * 64 + i * 16 + lg * 4 + r;
                float scale = bn_gamma[row] * rsqrtf(bn_var[row] + 1e-5f);
                float mn = bn_mean[row], bt = bn_beta[row];
                #pragma unroll
                for (int j = 0; j < 4; ++j) {
                    float v = (acc[i][j][r] - mn) * scale + bt;
                    C[(long)row * N + n0 + wc * 64 + j * 16 + lr] = v / (1.0f + __expf(-v));
                }
            }
        }
    }
}

// ---------------------------------------------------------------------------
// Stage 2 v2: block = (32-row half, c, z). Stage 5 planes (34 rolled rows) as
// f32 in LDS; sliding 4-row register window; 8 outputs/thread as 4 row-pairs.
// ---------------------------------------------------------------------------
__global__ __launch_bounds__(256)
void shift_dw_kernel(const __hip_bfloat16* __restrict__ xexp,  // [z][1280][4096]
                     const float* __restrict__ weff,           // [5][256][9]
                     __hip_bfloat16* __restrict__ merged) {    // [z][256][4096]
    __shared__ float planes[NK][34][64];   // 43.5 KB
    const int t  = threadIdx.x;
    const int r0 = blockIdx.x * 32;        // 0 or 32
    const int c  = blockIdx.y;
    const int z  = blockIdx.z;
    const int shifts[NK] = {-4, -1, 2, 5, 8};
    const __hip_bfloat16* base = xexp + ((long)z * NEXP + (long)c * NK) * HW;

    // stage: 5 planes x 34 rolled rows x 64 cols, bf16 -> f32
    for (int idx = t; idx < NK * 34 * 8; idx += 256) {
        int k   = idx / (34 * 8);
        int rem = idx - k * (34 * 8);
        int rr  = rem >> 3, ch = (rem & 7) * 8;
        int grow = (r0 - 1 + rr - shifts[k]) & 63;
        bf16x8 v = *(const bf16x8*)(base + (long)k * HW + grow * 64 + ch);
        float f[8];
        #pragma unroll
        for (int i = 0; i < 8; ++i) {
            unsigned u = ((unsigned)(unsigned short)v[i]) << 16;
            f[i] = __uint_as_float(u);
        }
        *(float4*)&planes[k][rr][ch]     = (float4){f[0], f[1], f[2], f[3]};
        *(float4*)&planes[k][rr][ch + 4] = (float4){f[4], f[5], f[6], f[7]};
    }
    __syncthreads();

    const int j  = t & 63;
    const int ty = t >> 6;                 // 0..3
    const int pbase = ty * 8;              // rr of row p = (r0 + ty*8) - 1
    const bool topEdge = (r0 == 0)  && (ty == 0);   // p = -1 at rr = pbase
    const bool botEdge = (r0 == 32) && (ty == 3);   // p = 64 at rr = pbase+9

    float2 acc[4];
    #pragma unroll
    for (int i = 0; i < 4; ++i) acc[i] = (float2){0.f, 0.f};

    #pragma unroll
    for (int k = 0; k < NK; ++k) {
        const int s = shifts[k];
        const int cL = (j - 1 - s) & 63;
        const int cC = (j - s) & 63;
        const int cR = (j + 1 - s) & 63;
        const float* wp = &weff[((long)k * C2 + c) * 9];
        float w[9];
        #pragma unroll
        for (int i = 0; i < 9; ++i) w[i] = wp[i];
        if (j == 0)  { w[0] = 0.f; w[3] = 0.f; w[6] = 0.f; }
        if (j == 63) { w[2] = 0.f; w[5] = 0.f; w[8] = 0.f; }
        const float* pl = &planes[k][0][0];

        float vL[4], vC[4], vR[4];
        #pragma unroll
        for (int w4 = 0; w4 < 4; ++w4) {
            vL[w4] = pl[(pbase + w4) * 64 + cL];
            vC[w4] = pl[(pbase + w4) * 64 + cC];
            vR[w4] = pl[(pbase + w4) * 64 + cR];
        }
        if (topEdge) { vL[0] = 0.f; vC[0] = 0.f; vR[0] = 0.f; }

        #pragma unroll
        for (int pr = 0; pr < 4; ++pr) {
            #pragma unroll
            for (int u = 0; u < 3; ++u) {
                const int wi  = (2 * pr + u) & 3;
                const int wi2 = (2 * pr + u + 1) & 3;
                acc[pr].x += w[u*3+0] * vL[wi]  + w[u*3+1] * vC[wi]  + w[u*3+2] * vR[wi];
                acc[pr].y += w[u*3+0] * vL[wi2] + w[u*3+1] * vC[wi2] + w[u*3+2] * vR[wi2];
            }
            if (pr < 3) {
                const int na = (2 * pr) & 3, nb = (2 * pr + 1) & 3;
                const int ra = pbase + 2 * pr + 4, rb = pbase + 2 * pr + 5;
                vL[na] = pl[ra * 64 + cL]; vC[na] = pl[ra * 64 + cC]; vR[na] = pl[ra * 64 + cR];
                vL[nb] = pl[rb * 64 + cL]; vC[nb] = pl[rb * 64 + cC]; vR[nb] = pl[rb * 64 + cR];
                if (botEdge && pr == 2) { vL[nb] = 0.f; vC[nb] = 0.f; vR[nb] = 0.f; }
            }
        }
    }

    long outb = ((long)z * C2 + c) * HW + (long)(r0 + ty * 8) * 64 + j;
    #pragma unroll
    for (int pr = 0; pr < 4; ++pr) {
        merged[outb + (long)(2 * pr) * 64]     = __float2bfloat16(acc[pr].x);
        merged[outb + (long)(2 * pr + 1) * 64] = __float2bfloat16(acc[pr].y);
    }
}

// ---------------------------------------------------------------------------
extern "C" void kernel_launch(void* const* d_in, const int* in_sizes, int n_in,
                              void* d_out, int out_size, void* d_ws, size_t ws_size,
                              hipStream_t stream) {
    const float* x        = (const float*)d_in[0];
    const float* w_expand = (const float*)d_in[1];
    const float* w_path   = (const float*)d_in[2];
    const float* w_mix    = (const float*)d_in[3];
    const float* bn_gamma = (const float*)d_in[4];
    const float* bn_beta  = (const float*)d_in[5];
    const float* bn_mean  = (const float*)d_in[6];
    const float* bn_var   = (const float*)d_in[7];

    char* ws = (char*)d_ws;
    float* weff             = (float*)ws;
    __hip_bfloat16* wexp_bf = (__hip_bfloat16*)(ws + 65536);
    __hip_bfloat16* wmix_bf = (__hip_bfloat16*)(ws + 65536 + 655360);
    const size_t head = 1 << 20;

    const size_t xT_per  = (size_t)HW * C1 * 2;
    const size_t xe_per  = (size_t)NEXP * HW * 2;
    const size_t mg_per  = (size_t)C2 * HW * 2;
    const size_t mgT_per = (size_t)HW * C2 * 2;
    const size_t per_b = xT_per + xe_per + mg_per + mgT_per;

    int g = 1;
    if (ws_size > head + per_b) {
        size_t fit = (ws_size - head) / per_b;
        g = (int)(fit < NB ? fit : NB);
        if (g < 1) g = 1;
    }

    char* p = ws + head;
    __hip_bfloat16* xTb     = (__hip_bfloat16*)p; p += (size_t)g * xT_per;
    __hip_bfloat16* xexp    = (__hip_bfloat16*)p; p += (size_t)g * xe_per;
    __hip_bfloat16* merged  = (__hip_bfloat16*)p; p += (size_t)g * mg_per;
    __hip_bfloat16* mergedT = (__hip_bfloat16*)p;

    weff_kernel<<<(NK * C2 * 9 + 255) / 256, 256, 0, stream>>>(w_path, weff);
    cvt_bf16_kernel<<<(NEXP * C1 + 255) / 256, 256, 0, stream>>>(w_expand, wexp_bf, NEXP * C1);
    cvt_bf16_kernel<<<(C2 * C2 + 255) / 256, 256, 0, stream>>>(w_mix, wmix_bf, C2 * C2);

    for (int b0 = 0; b0 < NB; b0 += g) {
        int gb = (NB - b0) < g ? (NB - b0) : g;
        transpose_bf16_kernel<float><<<dim3(HW / 32, C1 / 32, gb), 256, 0, stream>>>(
            x + (size_t)b0 * C1 * HW, xTb, C1, HW, (long)C1 * HW, (long)HW * C1);
        gemm_mfma_kernel<true><<<dim3(HW / 128, NEXP / 128, gb), 256, 0, stream>>>(
            wexp_bf, xTb, xexp, NEXP, HW, C1,
            (long)HW * C1, (long)NEXP * HW, 0, 0,
            nullptr, nullptr, nullptr, nullptr);
        shift_dw_kernel<<<dim3(2, C2, gb), 256, 0, stream>>>(xexp, weff, merged);
        transpose_bf16_kernel<__hip_bfloat16><<<dim3(HW / 32, C2 / 32, gb), 256, 0, stream>>>(
            merged, mergedT, C2, HW, (long)C2 * HW, (long)HW * C2);
        gemm_mfma_kernel<false><<<dim3(HW / 128, C2 / 128, gb), 256, 0, stream>>>(
            wmix_bf, mergedT, d_out, C2, HW, C2,
            (long)HW * C2, (long)C2 * HW, 0, b0,
            bn_gamma, bn_beta, bn_mean, bn_var);
    }
}

// Round 4
// 248.179 us; speedup vs baseline: 4.3769x; 1.1128x over previous
//
#include <hip/hip_runtime.h>
#include <hip/hip_bf16.h>
#include <math.h>

#define NB   16
#define C1   256
#define C2   256
#define NK   5
#define NEXP (C2 * NK)   // 1280
#define HW   4096

typedef __attribute__((ext_vector_type(8))) short bf16x8;
typedef __attribute__((ext_vector_type(4))) float f32x4;

#define GLOAD_LDS16(g, l) __builtin_amdgcn_global_load_lds( \
    (const __attribute__((address_space(1))) void*)(g), \
    (__attribute__((address_space(3))) void*)(l), 16, 0, 0)

// B-tile LDS swizzle: permute 16B chunks within each 64B row by n
__device__ __forceinline__ int bswz(int n, int kByte) {
    return n * 64 + (kByte ^ (((n >> 1) & 3) << 4));
}

// ---------------------------------------------------------------------------
__global__ void weff_kernel(const float* __restrict__ w_path, float* __restrict__ weff) {
    int idx = blockIdx.x * 256 + threadIdx.x;
    if (idx >= NK * C2 * 9) return;
    float s = 0.f;
    #pragma unroll
    for (int p = 0; p < 3; ++p)
        s += w_path[(long)p * NK * C2 * 9 + idx];
    weff[idx] = s;
}

__global__ void cvt_bf16_kernel(const float* __restrict__ in, __hip_bfloat16* __restrict__ out, int n) {
    int i = blockIdx.x * 256 + threadIdx.x;
    if (i < n) out[i] = __float2bfloat16(in[i]);
}

// ---------------------------------------------------------------------------
// MFMA bf16 GEMM, 128x128 tile, BK=32, 4 waves.
// A: bf16 [M][K] row-major, staged via global_load_lds (linear).
// B: [K][N] row-major (fp32 if FP32B else bf16), reg-staged with fused
//    transpose+convert into Bs[n][k] (XOR-swizzled), so no pre-transpose.
// ---------------------------------------------------------------------------
template <bool FP32B, bool OUT_BF16>
__global__ __launch_bounds__(256)
void gemm_mfma_kernel(const __hip_bfloat16* __restrict__ A,   // [M][K]
                      const void* __restrict__ B_all,         // [z][K][N]
                      void* __restrict__ C_all, int M, int N, int K,
                      long bStrideB, long bStrideC, int bOffB, int bOffC,
                      const float* __restrict__ bn_gamma, const float* __restrict__ bn_beta,
                      const float* __restrict__ bn_mean, const float* __restrict__ bn_var) {
    __shared__ __align__(16) short As[128 * 32];
    __shared__ __align__(16) short Bs[128 * 32];
    const int z = blockIdx.z;
    const int n0 = blockIdx.x * 128;
    const int m0 = blockIdx.y * 128;
    const int t = threadIdx.x;
    const int lane = t & 63;
    const int wid = t >> 6;
    const int wr = wid >> 1, wc = wid & 1;
    const int lr = lane & 15, lg = lane >> 4;
    const int sr = t >> 2;        // A staging row 0..63
    const int sc = (t & 3) * 8;   // A staging k-offset

    const __hip_bfloat16* aP0 = &A[(long)(m0 + sr) * K + sc];
    const __hip_bfloat16* aP1 = &A[(long)(m0 + 64 + sr) * K + sc];
    short* aD0 = &As[sr * 32 + sc];
    short* aD1 = &As[(64 + sr) * 32 + sc];

    // B staging: thread -> (n, kg); loads 16 k-strided elems at column n0+n
    const int bn = t & 127;
    const int kg = t >> 7;               // 0/1 -> k 0..15 / 16..31
    const float* Bf = (const float*)B_all + (long)(bOffB + z) * bStrideB + n0 + bn;
    const short* Bh = (const short*)B_all + (long)(bOffB + z) * bStrideB + n0 + bn;
    char* bD0 = (char*)Bs + bswz(bn, kg * 32);
    char* bD1 = (char*)Bs + bswz(bn, kg * 32 + 16);

    // B fragment byte offsets (4 n-values per wave-quadrant)
    int bOff[4];
    #pragma unroll
    for (int i = 0; i < 4; ++i)
        bOff[i] = bswz(wc * 64 + i * 16 + lr, lg * 16);

    f32x4 acc[4][4];
    #pragma unroll
    for (int i = 0; i < 4; ++i)
        #pragma unroll
        for (int j = 0; j < 4; ++j)
            acc[i][j] = (f32x4){0.f, 0.f, 0.f, 0.f};

    for (int k0 = 0; k0 < K; k0 += 32) {
        // issue B global loads early (reg staging)
        bf16x8 pk0, pk1;
        #pragma unroll
        for (int i = 0; i < 8; ++i) {
            if constexpr (FP32B) {
                float v0 = Bf[(long)(k0 + kg * 16 + i) * N];
                float v1 = Bf[(long)(k0 + kg * 16 + 8 + i) * N];
                __hip_bfloat16 h0 = __float2bfloat16(v0);
                __hip_bfloat16 h1 = __float2bfloat16(v1);
                pk0[i] = *reinterpret_cast<short*>(&h0);
                pk1[i] = *reinterpret_cast<short*>(&h1);
            } else {
                pk0[i] = Bh[(long)(k0 + kg * 16 + i) * N];
                pk1[i] = Bh[(long)(k0 + kg * 16 + 8 + i) * N];
            }
        }
        __syncthreads();                 // prior iter's LDS reads complete
        GLOAD_LDS16(aP0 + k0, aD0);
        GLOAD_LDS16(aP1 + k0, aD1);
        *(bf16x8*)bD0 = pk0;
        *(bf16x8*)bD1 = pk1;
        __syncthreads();                 // drains vmcnt+lgkm before use
        bf16x8 af[4], bfr[4];
        #pragma unroll
        for (int i = 0; i < 4; ++i) {
            af[i]  = *(const bf16x8*)&As[(wr * 64 + i * 16 + lr) * 32 + lg * 8];
            bfr[i] = *(const bf16x8*)((char*)Bs + bOff[i]);
        }
        #pragma unroll
        for (int i = 0; i < 4; ++i)
            #pragma unroll
            for (int j = 0; j < 4; ++j)
                acc[i][j] = __builtin_amdgcn_mfma_f32_16x16x32_bf16(af[i], bfr[j], acc[i][j], 0, 0, 0);
    }

    // C/D: col = lane&15, row = (lane>>4)*4 + reg
    if constexpr (OUT_BF16) {
        __hip_bfloat16* C = (__hip_bfloat16*)C_all + (long)(bOffC + z) * bStrideC;
        #pragma unroll
        for (int i = 0; i < 4; ++i) {
            #pragma unroll
            for (int r = 0; r < 4; ++r) {
                long row = m0 + wr * 64 + i * 16 + lg * 4 + r;
                #pragma unroll
                for (int j = 0; j < 4; ++j)
                    C[row * N + n0 + wc * 64 + j * 16 + lr] = __float2bfloat16(acc[i][j][r]);
            }
        }
    } else {
        float* C = (float*)C_all + (long)(bOffC + z) * bStrideC;
        #pragma unroll
        for (int i = 0; i < 4; ++i) {
            #pragma unroll
            for (int r = 0; r < 4; ++r) {
                int row = m0 + wr * 64 + i * 16 + lg * 4 + r;
                float scale = bn_gamma[row] * rsqrtf(bn_var[row] + 1e-5f);
                float mn = bn_mean[row], bt = bn_beta[row];
                #pragma unroll
                for (int j = 0; j < 4; ++j) {
                    float v = (acc[i][j][r] - mn) * scale + bt;
                    C[(long)row * N + n0 + wc * 64 + j * 16 + lr] = v / (1.0f + __expf(-v));
                }
            }
        }
    }
}

// ---------------------------------------------------------------------------
// Stage 2: roll + zero-padded depthwise 3x3 + sum over 5 shift groups.
// Planes staged as bf16 (21.76 KB LDS -> ~7 blocks/CU); sliding 4-row window.
// ---------------------------------------------------------------------------
__global__ __launch_bounds__(256)
void shift_dw_kernel(const __hip_bfloat16* __restrict__ xexp,  // [z][1280][4096]
                     const float* __restrict__ weff,           // [5][256][9]
                     __hip_bfloat16* __restrict__ merged) {    // [z][256][4096]
    __shared__ __align__(16) __hip_bfloat16 sd[NK * 34 * 64];  // 21760 B
    const int t  = threadIdx.x;
    const int r0 = blockIdx.x * 32;        // 0 or 32
    const int c  = blockIdx.y;
    const int z  = blockIdx.z;
    const int shifts[NK] = {-4, -1, 2, 5, 8};
    const __hip_bfloat16* base = xexp + ((long)z * NEXP + (long)c * NK) * HW;

    // stage: 5 planes x 34 rolled rows x 64 cols, straight bf16 copies
    for (int idx = t; idx < NK * 34 * 8; idx += 256) {
        int k   = idx / (34 * 8);
        int rem = idx - k * (34 * 8);
        int rr  = rem >> 3, ch = (rem & 7) * 8;
        int grow = (r0 - 1 + rr - shifts[k]) & 63;
        *(bf16x8*)&sd[(k * 34 + rr) * 64 + ch] =
            *(const bf16x8*)(base + (long)k * HW + grow * 64 + ch);
    }
    __syncthreads();

    const int j  = t & 63;
    const int ty = t >> 6;                 // 0..3
    const int pbase = ty * 8;              // rr of row (r0 + ty*8) - 1
    const bool topEdge = (r0 == 0)  && (ty == 0);
    const bool botEdge = (r0 == 32) && (ty == 3);

    float2 acc[4];
    #pragma unroll
    for (int i = 0; i < 4; ++i) acc[i] = (float2){0.f, 0.f};

    #pragma unroll
    for (int k = 0; k < NK; ++k) {
        const int s = shifts[k];
        const int cL = (j - 1 - s) & 63;
        const int cC = (j - s) & 63;
        const int cR = (j + 1 - s) & 63;
        const float* wp = &weff[((long)k * C2 + c) * 9];
        float w[9];
        #pragma unroll
        for (int i = 0; i < 9; ++i) w[i] = wp[i];
        if (j == 0)  { w[0] = 0.f; w[3] = 0.f; w[6] = 0.f; }
        if (j == 63) { w[2] = 0.f; w[5] = 0.f; w[8] = 0.f; }
        const __hip_bfloat16* pl = &sd[k * 34 * 64];

        float vL[4], vC[4], vR[4];
        #pragma unroll
        for (int w4 = 0; w4 < 4; ++w4) {
            vL[w4] = __bfloat162float(pl[(pbase + w4) * 64 + cL]);
            vC[w4] = __bfloat162float(pl[(pbase + w4) * 64 + cC]);
            vR[w4] = __bfloat162float(pl[(pbase + w4) * 64 + cR]);
        }
        if (topEdge) { vL[0] = 0.f; vC[0] = 0.f; vR[0] = 0.f; }

        #pragma unroll
        for (int pr = 0; pr < 4; ++pr) {
            #pragma unroll
            for (int u = 0; u < 3; ++u) {
                const int wi  = (2 * pr + u) & 3;
                const int wi2 = (2 * pr + u + 1) & 3;
                acc[pr].x += w[u*3+0] * vL[wi]  + w[u*3+1] * vC[wi]  + w[u*3+2] * vR[wi];
                acc[pr].y += w[u*3+0] * vL[wi2] + w[u*3+1] * vC[wi2] + w[u*3+2] * vR[wi2];
            }
            if (pr < 3) {
                const int na = (2 * pr) & 3, nb = (2 * pr + 1) & 3;
                const int ra = pbase + 2 * pr + 4, rb = pbase + 2 * pr + 5;
                vL[na] = __bfloat162float(pl[ra * 64 + cL]);
                vC[na] = __bfloat162float(pl[ra * 64 + cC]);
                vR[na] = __bfloat162float(pl[ra * 64 + cR]);
                vL[nb] = __bfloat162float(pl[rb * 64 + cL]);
                vC[nb] = __bfloat162float(pl[rb * 64 + cC]);
                vR[nb] = __bfloat162float(pl[rb * 64 + cR]);
                if (botEdge && pr == 2) { vL[nb] = 0.f; vC[nb] = 0.f; vR[nb] = 0.f; }
            }
        }
    }

    long outb = ((long)z * C2 + c) * HW + (long)(r0 + ty * 8) * 64 + j;
    #pragma unroll
    for (int pr = 0; pr < 4; ++pr) {
        merged[outb + (long)(2 * pr) * 64]     = __float2bfloat16(acc[pr].x);
        merged[outb + (long)(2 * pr + 1) * 64] = __float2bfloat16(acc[pr].y);
    }
}

// ---------------------------------------------------------------------------
extern "C" void kernel_launch(void* const* d_in, const int* in_sizes, int n_in,
                              void* d_out, int out_size, void* d_ws, size_t ws_size,
                              hipStream_t stream) {
    const float* x        = (const float*)d_in[0];
    const float* w_expand = (const float*)d_in[1];
    const float* w_path   = (const float*)d_in[2];
    const float* w_mix    = (const float*)d_in[3];
    const float* bn_gamma = (const float*)d_in[4];
    const float* bn_beta  = (const float*)d_in[5];
    const float* bn_mean  = (const float*)d_in[6];
    const float* bn_var   = (const float*)d_in[7];

    char* ws = (char*)d_ws;
    float* weff             = (float*)ws;
    __hip_bfloat16* wexp_bf = (__hip_bfloat16*)(ws + 65536);
    __hip_bfloat16* wmix_bf = (__hip_bfloat16*)(ws + 65536 + 655360);
    const size_t head = 1 << 20;

    const size_t xe_per = (size_t)NEXP * HW * 2;   // 10 MB
    const size_t mg_per = (size_t)C2 * HW * 2;     // 2 MB
    const size_t per_b = xe_per + mg_per;          // 12 MB

    int g = 1;
    if (ws_size > head + per_b) {
        size_t fit = (ws_size - head) / per_b;
        g = (int)(fit < NB ? fit : NB);
        if (g < 1) g = 1;
    }

    char* p = ws + head;
    __hip_bfloat16* xexp   = (__hip_bfloat16*)p; p += (size_t)g * xe_per;
    __hip_bfloat16* merged = (__hip_bfloat16*)p;

    weff_kernel<<<(NK * C2 * 9 + 255) / 256, 256, 0, stream>>>(w_path, weff);
    cvt_bf16_kernel<<<(NEXP * C1 + 255) / 256, 256, 0, stream>>>(w_expand, wexp_bf, NEXP * C1);
    cvt_bf16_kernel<<<(C2 * C2 + 255) / 256, 256, 0, stream>>>(w_mix, wmix_bf, C2 * C2);

    for (int b0 = 0; b0 < NB; b0 += g) {
        int gb = (NB - b0) < g ? (NB - b0) : g;
        // expand: A = wexp_bf [1280x256], B = x [z][256][4096] fp32 -> xexp bf16
        gemm_mfma_kernel<true, true><<<dim3(HW / 128, NEXP / 128, gb), 256, 0, stream>>>(
            wexp_bf, x, xexp, NEXP, HW, C1,
            (long)C1 * HW, (long)NEXP * HW, b0, 0,
            nullptr, nullptr, nullptr, nullptr);
        // roll + dw3x3 + merge
        shift_dw_kernel<<<dim3(2, C2, gb), 256, 0, stream>>>(xexp, weff, merged);
        // mix: A = wmix_bf [256x256], B = merged [z][256][4096] bf16 -> d_out fp32
        gemm_mfma_kernel<false, false><<<dim3(HW / 128, C2 / 128, gb), 256, 0, stream>>>(
            wmix_bf, merged, d_out, C2, HW, C2,
            (long)C2 * HW, (long)C2 * HW, 0, b0,
            bn_gamma, bn_beta, bn_mean, bn_var);
    }
}